// Round 1
// baseline (424.689 us; speedup 1.0000x reference)
//
#include <hip/hip_runtime.h>
#include <math.h>

#define EMBED 384
#define HID 64
#define NE 4

// Main kernel: one lane per token, 64 tokens per wave, 256 threads/block.
__global__ __launch_bounds__(256) void router_main(
    const float* __restrict__ x, const float* __restrict__ lnw,
    const float* __restrict__ lnb, const float* __restrict__ w1,
    const float* __restrict__ w2, float* __restrict__ out,
    float* __restrict__ ws, int ntok)
{
  const int lane = (int)(threadIdx.x & 63);
  const int wid  = (int)(blockIdx.x * (blockDim.x >> 6)) + (int)(threadIdx.x >> 6);
  const int token = (wid << 6) + lane;
  if (token >= ntok) return;

  const float* xrow = x + (size_t)token * EMBED;

  // ---- LayerNorm statistics (per-lane, no cross-lane traffic) ----
  float s = 0.f, s2 = 0.f;
  #pragma unroll 4
  for (int k = 0; k < EMBED / 4; ++k) {
    float4 v = reinterpret_cast<const float4*>(xrow)[k];
    s += (v.x + v.y) + (v.z + v.w);
    s2 = fmaf(v.x, v.x, s2);
    s2 = fmaf(v.y, v.y, s2);
    s2 = fmaf(v.z, v.z, s2);
    s2 = fmaf(v.w, v.w, s2);
  }
  const float mu   = s * (1.f / EMBED);
  const float var  = fmaf(-mu, mu, s2 * (1.f / EMBED));
  const float rstd = rsqrtf(var + 1e-5f);

  // ---- GEMM1: hidden[j] = sum_d hln[d] * w1[d][j]  (w1 reads wave-uniform) ----
  float acc[HID];
  #pragma unroll
  for (int j = 0; j < HID; ++j) acc[j] = 0.f;

  for (int d = 0; d < EMBED; d += 4) {
    float4 v  = *reinterpret_cast<const float4*>(xrow + d);
    float4 lw = *reinterpret_cast<const float4*>(lnw + d);   // uniform -> s_load
    float4 lb = *reinterpret_cast<const float4*>(lnb + d);   // uniform -> s_load
    const float h0 = fmaf((v.x - mu) * rstd, lw.x, lb.x);
    const float h1 = fmaf((v.y - mu) * rstd, lw.y, lb.y);
    const float h2 = fmaf((v.z - mu) * rstd, lw.z, lb.z);
    const float h3 = fmaf((v.w - mu) * rstd, lw.w, lb.w);
    const float* __restrict__ w1r = w1 + d * HID;            // uniform base
    #pragma unroll
    for (int j = 0; j < HID; ++j) {
      float a = acc[j];
      a = fmaf(h0, w1r[j], a);
      a = fmaf(h1, w1r[HID + j], a);
      a = fmaf(h2, w1r[2 * HID + j], a);
      a = fmaf(h3, w1r[3 * HID + j], a);
      acc[j] = a;
    }
  }

  // ---- GELU (exact) + GEMM2 (w2 reads wave-uniform) ----
  float logit[NE] = {0.f, 0.f, 0.f, 0.f};
  #pragma unroll
  for (int j = 0; j < HID; ++j) {
    const float hv = acc[j];
    const float g  = 0.5f * hv * (1.f + erff(hv * 0.7071067811865475f));
    #pragma unroll
    for (int e = 0; e < NE; ++e)
      logit[e] = fmaf(g, w2[j * NE + e], logit[e]);
  }

  // ---- temperature + softmax ----
  const float invT = 0.5f;  // T = max(2.0, 0.1) = 2.0
  float l0 = logit[0] * invT, l1 = logit[1] * invT,
        l2 = logit[2] * invT, l3 = logit[3] * invT;
  float m = fmaxf(fmaxf(l0, l1), fmaxf(l2, l3));
  float e0 = __expf(l0 - m), e1 = __expf(l1 - m),
        e2 = __expf(l2 - m), e3 = __expf(l3 - m);
  // use precise expf for safety
  e0 = expf(l0 - m); e1 = expf(l1 - m); e2 = expf(l2 - m); e3 = expf(l3 - m);
  const float denom = 1.f / (e0 + e1 + e2 + e3);
  const float p0 = e0 * denom, p1 = e1 * denom, p2 = e2 * denom, p3 = e3 * denom;

  // ---- argmax, first-occurrence tie-break (matches lax.top_k) ----
  int best = 0;
  float bp = p0;
  if (p1 > bp) { bp = p1; best = 1; }
  if (p2 > bp) { bp = p2; best = 2; }
  if (p3 > bp) { bp = p3; best = 3; }

  // ---- stores ----
  // layout: probs[4N] | indices[N] | aux[1] | probs[4N]
  float4 pv = make_float4(p0, p1, p2, p3);
  *reinterpret_cast<float4*>(out + (size_t)token * 4) = pv;
  out[(size_t)ntok * 4 + token] = (float)best;
  float* o3 = out + (size_t)ntok * 5 + 1 + (size_t)token * 4;  // odd offset: scalar stores
  o3[0] = p0; o3[1] = p1; o3[2] = p2; o3[3] = p3;

  // ---- aux-loss partial reduction (wave-level, then 8 atomics per wave) ----
  float pr[NE] = {p0, p1, p2, p3};
  #pragma unroll
  for (int e = 0; e < NE; ++e) {
    float a = pr[e];
    float c = (e == best) ? 1.f : 0.f;
    #pragma unroll
    for (int off = 32; off; off >>= 1) {
      a += __shfl_xor(a, off);
      c += __shfl_xor(c, off);
    }
    if (lane == 0) {
      atomicAdd(&ws[e], a);        // sum of probs per expert
      atomicAdd(&ws[NE + e], c);   // count of argmax hits per expert
    }
  }
}

__global__ void router_finalize(const float* __restrict__ ws,
                                float* __restrict__ out, int ntok)
{
  if (threadIdx.x == 0 && blockIdx.x == 0) {
    const float invN = 1.f / (float)ntok;
    float aux = 0.f;
    #pragma unroll
    for (int e = 0; e < NE; ++e) {
      const float P = ws[e] * invN;        // mean prob
      const float f = ws[NE + e] * invN;   // routed fraction
      aux = fmaf(f, P, aux);
    }
    out[(size_t)ntok * 5] = (float)NE * aux;
  }
}

extern "C" void kernel_launch(void* const* d_in, const int* in_sizes, int n_in,
                              void* d_out, int out_size, void* d_ws, size_t ws_size,
                              hipStream_t stream) {
  const float* x   = (const float*)d_in[0];
  const float* lnw = (const float*)d_in[1];
  const float* lnb = (const float*)d_in[2];
  const float* w1  = (const float*)d_in[3];
  const float* w2  = (const float*)d_in[4];
  float* out = (float*)d_out;
  float* ws  = (float*)d_ws;

  const int ntok = in_sizes[0] / EMBED;   // 131072

  // zero the 8 accumulator slots (ws is poisoned 0xAA and never re-poisoned)
  hipMemsetAsync(d_ws, 0, 2 * NE * sizeof(float), stream);

  const int threads = 256;                 // 4 waves/block, 64 tokens/wave
  const int blocks  = (ntok + threads - 1) / threads;
  router_main<<<blocks, threads, 0, stream>>>(x, lnw, lnb, w1, w2, out, ws, ntok);
  router_finalize<<<1, 64, 0, stream>>>(ws, out, ntok);
}

// Round 2
// 240.751 us; speedup vs baseline: 1.7640x; 1.7640x over previous
//
#include <hip/hip_runtime.h>
#include <math.h>

#define EMBED 384
#define HID 64
#define NE 4
#define M 2                 // tokens per thread
#define TPB 256             // threads per block
#define TOK_PER_BLOCK (TPB * M)   // 512

__global__ __launch_bounds__(TPB, 1) void router_main(
    const float* __restrict__ x, const float* __restrict__ lnw,
    const float* __restrict__ lnb, const float* __restrict__ w1,
    const float* __restrict__ w2, float* __restrict__ out,
    float* __restrict__ ws, int ntok)
{
  __shared__ float red[2 * NE];   // block-level aux reduction

  if (threadIdx.x < 2 * NE) red[threadIdx.x] = 0.f;
  __syncthreads();

  // token mapping: wave v handles tokens [blk*512 + v*128, +128);
  // lane L -> t0 = base + L, t1 = t0 + 64  (coalesced stores per wave)
  const int lane = (int)(threadIdx.x & 63);
  const int wv   = (int)(threadIdx.x >> 6);
  const int base = (int)blockIdx.x * TOK_PER_BLOCK + wv * (64 * M);
  int t[M];
  t[0] = base + lane;
  t[1] = base + 64 + lane;
  if (t[0] >= ntok) return;
  bool valid1 = (t[1] < ntok);
  if (!valid1) t[1] = t[0];     // clamp (never happens for 131072)

  // ---- pass 1: LN stats per token ----
  float mu[M], rstd[M];
  #pragma unroll
  for (int m = 0; m < M; ++m) {
    const float4* xr = reinterpret_cast<const float4*>(x + (size_t)t[m] * EMBED);
    float s = 0.f, s2 = 0.f;
    #pragma unroll 4
    for (int k = 0; k < EMBED / 4; ++k) {
      float4 v = xr[k];
      s += (v.x + v.y) + (v.z + v.w);
      s2 = fmaf(v.x, v.x, s2); s2 = fmaf(v.y, v.y, s2);
      s2 = fmaf(v.z, v.z, s2); s2 = fmaf(v.w, v.w, s2);
    }
    mu[m] = s * (1.f / EMBED);
    float var = fmaf(-mu[m], mu[m], s2 * (1.f / EMBED));
    rstd[m] = rsqrtf(var + 1e-5f);
  }

  // ---- pass 2: GEMM1 with register tiling ----
  float acc[M][HID];
  #pragma unroll
  for (int m = 0; m < M; ++m)
    #pragma unroll
    for (int j = 0; j < HID; ++j) acc[m][j] = 0.f;

  for (int dq = 0; dq < EMBED / 4; ++dq) {
    const int d = dq * 4;
    float4 lw = *reinterpret_cast<const float4*>(lnw + d);
    float4 lb = *reinterpret_cast<const float4*>(lnb + d);
    float h[M][4];
    #pragma unroll
    for (int m = 0; m < M; ++m) {
      float4 v = *reinterpret_cast<const float4*>(x + (size_t)t[m] * EMBED + d);
      h[m][0] = fmaf((v.x - mu[m]) * rstd[m], lw.x, lb.x);
      h[m][1] = fmaf((v.y - mu[m]) * rstd[m], lw.y, lb.y);
      h[m][2] = fmaf((v.z - mu[m]) * rstd[m], lw.z, lb.z);
      h[m][3] = fmaf((v.w - mu[m]) * rstd[m], lw.w, lb.w);
    }
    const float* __restrict__ w1r = w1 + d * HID;
    #pragma unroll
    for (int jq = 0; jq < HID / 4; ++jq) {
      float4 w0 = *reinterpret_cast<const float4*>(w1r + jq * 4);
      float4 w1v = *reinterpret_cast<const float4*>(w1r + HID + jq * 4);
      float4 w2v = *reinterpret_cast<const float4*>(w1r + 2 * HID + jq * 4);
      float4 w3v = *reinterpret_cast<const float4*>(w1r + 3 * HID + jq * 4);
      #pragma unroll
      for (int m = 0; m < M; ++m) {
        float a0 = acc[m][jq * 4 + 0], a1 = acc[m][jq * 4 + 1];
        float a2 = acc[m][jq * 4 + 2], a3 = acc[m][jq * 4 + 3];
        a0 = fmaf(h[m][0], w0.x, a0); a1 = fmaf(h[m][0], w0.y, a1);
        a2 = fmaf(h[m][0], w0.z, a2); a3 = fmaf(h[m][0], w0.w, a3);
        a0 = fmaf(h[m][1], w1v.x, a0); a1 = fmaf(h[m][1], w1v.y, a1);
        a2 = fmaf(h[m][1], w1v.z, a2); a3 = fmaf(h[m][1], w1v.w, a3);
        a0 = fmaf(h[m][2], w2v.x, a0); a1 = fmaf(h[m][2], w2v.y, a1);
        a2 = fmaf(h[m][2], w2v.z, a2); a3 = fmaf(h[m][2], w2v.w, a3);
        a0 = fmaf(h[m][3], w3v.x, a0); a1 = fmaf(h[m][3], w3v.y, a1);
        a2 = fmaf(h[m][3], w3v.z, a2); a3 = fmaf(h[m][3], w3v.w, a3);
        acc[m][jq * 4 + 0] = a0; acc[m][jq * 4 + 1] = a1;
        acc[m][jq * 4 + 2] = a2; acc[m][jq * 4 + 3] = a3;
      }
    }
  }

  // ---- epilogue per token ----
  float psum[NE] = {0.f, 0.f, 0.f, 0.f};
  float pcnt[NE] = {0.f, 0.f, 0.f, 0.f};

  #pragma unroll
  for (int m = 0; m < M; ++m) {
    float logit[NE] = {0.f, 0.f, 0.f, 0.f};
    #pragma unroll
    for (int j = 0; j < HID; ++j) {
      const float hv = acc[m][j];
      const float g  = 0.5f * hv * (1.f + erff(hv * 0.7071067811865475f));
      #pragma unroll
      for (int e = 0; e < NE; ++e)
        logit[e] = fmaf(g, w2[j * NE + e], logit[e]);
    }
    const float l0 = logit[0] * 0.5f, l1 = logit[1] * 0.5f,
                l2 = logit[2] * 0.5f, l3 = logit[3] * 0.5f;
    const float mx = fmaxf(fmaxf(l0, l1), fmaxf(l2, l3));
    const float e0 = expf(l0 - mx), e1 = expf(l1 - mx),
                e2 = expf(l2 - mx), e3 = expf(l3 - mx);
    const float inv = 1.f / (e0 + e1 + e2 + e3);
    const float p0 = e0 * inv, p1 = e1 * inv, p2 = e2 * inv, p3 = e3 * inv;

    int best = 0; float bp = p0;
    if (p1 > bp) { bp = p1; best = 1; }
    if (p2 > bp) { bp = p2; best = 2; }
    if (p3 > bp) { bp = p3; best = 3; }

    const bool live = (m == 0) || valid1;
    if (live) {
      const int tok = t[m];
      *reinterpret_cast<float4*>(out + (size_t)tok * 4) = make_float4(p0, p1, p2, p3);
      out[(size_t)ntok * 4 + tok] = (float)best;
      float* o3 = out + (size_t)ntok * 5 + 1 + (size_t)tok * 4;
      o3[0] = p0; o3[1] = p1; o3[2] = p2; o3[3] = p3;
      psum[0] += p0; psum[1] += p1; psum[2] += p2; psum[3] += p3;
      pcnt[best] += 1.f;
    }
  }

  // ---- aux reduction: wave -> LDS -> global ----
  #pragma unroll
  for (int e = 0; e < NE; ++e) {
    float a = psum[e], c = pcnt[e];
    #pragma unroll
    for (int off = 32; off; off >>= 1) {
      a += __shfl_xor(a, off);
      c += __shfl_xor(c, off);
    }
    if (lane == 0) {
      atomicAdd(&red[e], a);
      atomicAdd(&red[NE + e], c);
    }
  }
  __syncthreads();
  if (threadIdx.x < 2 * NE) atomicAdd(&ws[threadIdx.x], red[threadIdx.x]);
}

__global__ void router_finalize(const float* __restrict__ ws,
                                float* __restrict__ out, int ntok)
{
  if (threadIdx.x == 0 && blockIdx.x == 0) {
    const float invN = 1.f / (float)ntok;
    float aux = 0.f;
    #pragma unroll
    for (int e = 0; e < NE; ++e)
      aux = fmaf(ws[NE + e] * invN, ws[e] * invN, aux);
    out[(size_t)ntok * 5] = (float)NE * aux;
  }
}

extern "C" void kernel_launch(void* const* d_in, const int* in_sizes, int n_in,
                              void* d_out, int out_size, void* d_ws, size_t ws_size,
                              hipStream_t stream) {
  const float* x   = (const float*)d_in[0];
  const float* lnw = (const float*)d_in[1];
  const float* lnb = (const float*)d_in[2];
  const float* w1  = (const float*)d_in[3];
  const float* w2  = (const float*)d_in[4];
  float* out = (float*)d_out;
  float* ws  = (float*)d_ws;

  const int ntok = in_sizes[0] / EMBED;   // 131072

  hipMemsetAsync(d_ws, 0, 2 * NE * sizeof(float), stream);

  const int blocks = (ntok + TOK_PER_BLOCK - 1) / TOK_PER_BLOCK;
  router_main<<<blocks, TPB, 0, stream>>>(x, lnw, lnb, w1, w2, out, ws, ntok);
  router_finalize<<<1, 64, 0, stream>>>(ws, out, ntok);
}